// Round 8
// baseline (1215.206 us; speedup 1.0000x reference)
//
#include <hip/hip_runtime.h>

// GoL CNN v9: v8 barrier-free structure + PINNED distance-1 pipeline.
// Evidence: v6/v8 compiler allocated 96/116 VGPR (double-buffer needs ~208)
// -> it sank prefetch loads to their uses; every wave serializes
// {issue 20 loads -> wait -> 16 MFMA} => ~16 B/cyc/CU on a 2.2 MB/layer
// stream (floor ~15 us/layer at 56-64 B/cyc). Fix: after each prefetch
// cluster, asm volatile s_waitcnt vmcnt(20) with "memory" clobber +
// sched_barrier(0). The clobber forbids sinking loads past the fence;
// vmcnt(20) waits only for the PREVIOUS channel's 20 loads (constant by
// induction), keeping the next channel's 20 in flight during MFMAs.
// Loop 2x-unrolled (static reg buffers, rule #20); last pair peeled for
// the vmcnt(0) drain. F-row offsets wave-uniform (SGPR) to save VGPRs.

typedef _Float16 f16;
typedef _Float16 f16x8 __attribute__((ext_vector_type(8)));
typedef float f32x4 __attribute__((ext_vector_type(4)));
typedef float f32x16 __attribute__((ext_vector_type(16)));
typedef int i4a __attribute__((ext_vector_type(4), aligned(4)));  // 16B ld, 4B align

// iterated wrap-pad index map, j in [0,94): middle j-31; borders alternate.
__device__ __forceinline__ int mwrap(int j) {
  int t = j - 31;
  if ((unsigned)t <= 31u) return t;          // middle
  if (t < 0) return (j & 1) ? 0 : 31;        // left border
  return (j & 1) ? 0 : 31;                   // right border
}

// hpad layout: [16b][32ch][32y][96x] f16 (x' in [0,94) valid)
// Wf frag-major: per layer, chunk=(c*32+ky)*2+kxh, then [lane(64)][8 f16]
//   lane: co=lane&31, s=lane>>5; elements w[co][c][ky][kxh*16+s*8+j]

// 16 MFMAs consuming register-resident fragments (no memory access).
#define MFMAC(AUSE, FD)                                                      \
  {                                                                          \
    _Pragma("unroll")                                                        \
    for (int kyi_ = 0; kyi_ < 4; ++kyi_) {                                   \
      _Pragma("unroll")                                                      \
      for (int kxh_ = 0; kxh_ < 2; ++kxh_) {                                 \
        const f16x8 a_ = AUSE[kyi_ * 2 + kxh_];                              \
        acc0 = __builtin_amdgcn_mfma_f32_32x32x16_f16(a_, FD[kyi_][kxh_],    \
                                                      acc0, 0, 0, 0);        \
        acc1 = __builtin_amdgcn_mfma_f32_32x32x16_f16(a_, FD[kyi_ + 2][kxh_],\
                                                      acc1, 0, 0, 0);        \
      }                                                                      \
    }                                                                        \
  }

// Pin point: previous channel's loads must be done; the just-issued 20 stay
// in flight. "memory" clobber forbids sinking the loads below this fence.
#define PIN20()                                          \
  asm volatile("s_waitcnt vmcnt(20)" ::: "memory");      \
  __builtin_amdgcn_sched_barrier(0);
#define PIN0()                                           \
  asm volatile("s_waitcnt vmcnt(0)" ::: "memory");       \
  __builtin_amdgcn_sched_barrier(0);

template <int CIN, bool RELU, bool PRE>
__global__ __launch_bounds__(512, 2) void gemm3(
    const void* __restrict__ Wv,       // PRE: f16 frag-major; else fp32 raw
    const f16* __restrict__ hp_in,     // [16][CIN][32][96]
    const float* __restrict__ bias,    // [32]
    f16* __restrict__ hp_out) {        // [16][32][32][96]
  __shared__ float Red[8][2][1024];    // 64 KB (reduction only)

  const int tid = threadIdx.x;
  const int lane = tid & 63;
  const int w = tid >> 6;        // wave 0..7: owns ky in {4w..4w+3}
  const int ox = lane & 31;      // B n-index / A m-index (co)
  const int s = lane >> 5;       // k-half within mfma

  const int pair0 = blockIdx.x * 2;
  const int b = pair0 >> 5;
  const int oy0 = pair0 & 31;    // pair0 even -> oy0, oy0+1 same batch

  // F addressing: per-lane base + wave-uniform row offsets (SGPR-resident).
  // acc0 (row oy0):   y = mwrap(2*oy0 + 4w + j), j=0..3
  // acc1 (row oy0+1): same rows shifted by 2 -> j=2..5
  const int bi = ox + 4 * s;
  const int* Rbase = (const int*)hp_in + (size_t)b * CIN * 32 * 48 + bi;
  int rowd[6];
#pragma unroll
  for (int j = 0; j < 6; ++j) rowd[j] = mwrap(2 * oy0 + 4 * w + j) * 48;

  f32x16 acc0 = {}, acc1 = {};   // per pair
  f16x8 A0[8], A1[8];
  f16x8 F0[6][2], F1[6][2];

  auto loadA = [&](int c, f16x8* dst) {
#pragma unroll
    for (int kyi = 0; kyi < 4; ++kyi) {
#pragma unroll
      for (int kxh = 0; kxh < 2; ++kxh) {
        const int ky = 4 * w + kyi;
        const int chunk = (c * 32 + ky) * 2 + kxh;
        if constexpr (PRE) {
          const f16* Wl = (const f16*)Wv;
          dst[kyi * 2 + kxh] = *(const f16x8*)(Wl + (size_t)chunk * 512 + lane * 8);
        } else {
          const float* Wl = (const float*)Wv;
          const float* sp = Wl + (((size_t)(ox * CIN + c) * 32 + ky) * 32 + kxh * 16 + s * 8);
          f32x4 u0 = *(const f32x4*)sp;
          f32x4 u1 = *(const f32x4*)(sp + 4);
          f16x8 v;
          v[0] = (f16)u0[0]; v[1] = (f16)u0[1]; v[2] = (f16)u0[2]; v[3] = (f16)u0[3];
          v[4] = (f16)u1[0]; v[5] = (f16)u1[1]; v[6] = (f16)u1[2]; v[7] = (f16)u1[3];
          dst[kyi * 2 + kxh] = v;
        }
      }
    }
  };
  // 12 B-fragments of channel c, straight from global (L1/L2-resident).
  auto loadF = [&](int c, f16x8 (*FD)[2]) {
    const int coff = c * 1536;  // 48*32 dwords per channel plane
#pragma unroll
    for (int j = 0; j < 6; ++j) {
      const int* R = Rbase + (rowd[j] + coff);
      FD[j][0] = __builtin_bit_cast(f16x8, *(const i4a*)(R));
      FD[j][1] = __builtin_bit_cast(f16x8, *(const i4a*)(R + 8));
    }
  };

  if constexpr (CIN == 1) {
    loadA(0, A0);
    loadF(0, F0);
    MFMAC(A0, F0);
  } else {
    static_assert(CIN >= 4 && CIN % 2 == 0, "CIN must be 1 or even >= 4");
    loadA(0, A0);
    loadF(0, F0);
#pragma unroll 1
    for (int c = 0; c < CIN - 2; c += 2) {
      loadA(c + 1, A1);          // 20-load prefetch cluster (pinned by fence)
      loadF(c + 1, F1);
      PIN20();                   // waits L(c); L(c+1) stays in flight
      MFMAC(A0, F0);             // c
      loadA(c + 2, A0);
      loadF(c + 2, F0);
      PIN20();                   // waits L(c+1); L(c+2) stays in flight
      MFMAC(A1, F1);             // c+1
    }
    // peeled tail pair (CIN-2, CIN-1): drain with exact counts
    loadA(CIN - 1, A1);
    loadF(CIN - 1, F1);
    PIN20();                     // waits L(CIN-2)
    MFMAC(A0, F0);               // CIN-2
    PIN0();                      // waits L(CIN-1)
    MFMAC(A1, F1);               // CIN-1
  }

  // one-shot 8-way K reduction: every wave dumps, all 512 threads re-reduce
  __syncthreads();               // (only cross-wave sync in the kernel)
#pragma unroll
  for (int r = 0; r < 16; ++r) {
    Red[w][0][r * 64 + lane] = acc0[r];
    Red[w][1][r * 64 + lane] = acc1[r];
  }
  __syncthreads();

#pragma unroll
  for (int k4 = 0; k4 < 4; ++k4) {
    const int o = tid + 512 * k4;          // 2048 outputs: [p][co][ox]
    const int p = o >> 10, co = (o >> 5) & 31, oxx = o & 31;
    const int idx = ((co & 3) + 4 * (co >> 3)) * 64 + ((co >> 2) & 1) * 32 + oxx;
    float v = bias[co];
#pragma unroll
    for (int w8 = 0; w8 < 8; ++w8) v += Red[w8][p][idx];
    if (RELU) v = fmaxf(v, 0.f);
    const f16 hv = (f16)v;
    f16* base = hp_out + ((size_t)(b * 32 + co) * 32 + (oy0 + p)) * 96;
    base[oxx + 31] = hv;
    if (oxx == 0) {
#pragma unroll
      for (int j = 1; j <= 29; j += 2) base[j] = hv;
#pragma unroll
      for (int j = 63; j <= 93; j += 2) base[j] = hv;
    }
    if (oxx == 31) {
#pragma unroll
      for (int j = 0; j <= 30; j += 2) base[j] = hv;
#pragma unroll
      for (int j = 64; j <= 92; j += 2) base[j] = hv;
    }
  }
}

// x (fp32 [16][1][32][32]) -> xpad f16 [16][1][32][96]
__global__ void pad_x_kernel(const float* __restrict__ x, f16* __restrict__ xp) {
  const int i = blockIdx.x * 256 + threadIdx.x;  // 16*32*94 = 48128
  if (i >= 48128) return;
  const int bq = i / 3008, r = i - bq * 3008;
  const int y = r / 94, j = r - y * 94;
  xp[bq * 3072 + y * 96 + j] = (f16)x[(bq * 32 + y) * 32 + mwrap(j)];
}

// build frag-major f16 weights: in_w (64 chunks) + 20 hidden layers (2048 each)
__global__ void convert_w3(const float* __restrict__ in_w,
                           const float* __restrict__ convs_w,
                           f16* __restrict__ WfIn, f16* __restrict__ WfH) {
  const int total = 4096 + 20 * 131072;  // units of (chunk,lane)
  for (int g = blockIdx.x * blockDim.x + threadIdx.x; g < total;
       g += gridDim.x * blockDim.x) {
    const float* src;
    f16* dst;
    int chunk, lanE, c, ky, kxh;
    if (g < 4096) {
      chunk = g >> 6; lanE = g & 63;
      kxh = chunk & 1; ky = chunk >> 1; c = 0;
      const int co = lanE & 31, ss = lanE >> 5;
      src = in_w + ((size_t)(co * 1 + 0) * 32 + ky) * 32 + kxh * 16 + ss * 8;
      dst = WfIn + (size_t)chunk * 512 + lanE * 8;
    } else {
      const int h = g - 4096;
      const int layer = h >> 17, r = h & 131071;
      chunk = r >> 6; lanE = r & 63;
      kxh = chunk & 1;
      const int t = chunk >> 1;
      ky = t & 31; c = t >> 5;
      const int co = lanE & 31, ss = lanE >> 5;
      src = convs_w + (size_t)layer * 1048576 +
            ((size_t)(co * 32 + c) * 32 + ky) * 32 + kxh * 16 + ss * 8;
      dst = WfH + (size_t)layer * 1048576 + (size_t)chunk * 512 + lanE * 8;
    }
    f32x4 u0 = *(const f32x4*)src;
    f32x4 u1 = *(const f32x4*)(src + 4);
    f16x8 v;
    v[0] = (f16)u0[0]; v[1] = (f16)u0[1]; v[2] = (f16)u0[2]; v[3] = (f16)u0[3];
    v[4] = (f16)u1[0]; v[5] = (f16)u1[1]; v[6] = (f16)u1[2]; v[7] = (f16)u1[3];
    *(f16x8*)dst = v;
  }
}

// 1x1 out conv from hpad final: out[b][0][oy][ox] fp32
__global__ void out_conv3(const f16* __restrict__ hp,
                          const float* __restrict__ ow,
                          const float* __restrict__ ob,
                          float* __restrict__ out) {
  const int o = blockIdx.x * 256 + threadIdx.x;  // 16384
  const int b = o >> 10, oy = (o >> 5) & 31, oxx = o & 31;
  float s = ob[0];
#pragma unroll
  for (int c = 0; c < 32; ++c)
    s += ow[c] * (float)hp[((size_t)(b * 32 + c) * 32 + oy) * 96 + oxx + 31];
  out[o] = s;
}

extern "C" void kernel_launch(void* const* d_in, const int* in_sizes, int n_in,
                              void* d_out, int out_size, void* d_ws,
                              size_t ws_size, hipStream_t stream) {
  const float* x = (const float*)d_in[0];
  const float* in_w = (const float*)d_in[1];
  const float* in_b = (const float*)d_in[2];
  const float* convs_w = (const float*)d_in[3];
  const float* convs_b = (const float*)d_in[4];
  const float* out_w = (const float*)d_in[5];
  const float* out_b = (const float*)d_in[6];
  float* out = (float*)d_out;

  char* ws = (char*)d_ws;
  f16* xpad = (f16*)ws;                               //    98,304 B
  f16* hpA = (f16*)(ws + 98304);                      // 3,145,728 B
  f16* hpB = (f16*)(ws + 98304 + 3145728);            // 3,145,728 B
  f16* WfIn = (f16*)(ws + 6389760);                   //    65,536 B
  f16* WfH = (f16*)(ws + 6455296);                    // 41,943,040 B
  const bool pre = (ws_size >= 48398336ull);

  pad_x_kernel<<<188, 256, 0, stream>>>(x, xpad);
  if (pre) convert_w3<<<2048, 256, 0, stream>>>(in_w, convs_w, WfIn, WfH);

  if (pre)
    gemm3<1, false, true><<<256, 512, 0, stream>>>(WfIn, xpad, in_b, hpA);
  else
    gemm3<1, false, false><<<256, 512, 0, stream>>>(in_w, xpad, in_b, hpA);

  for (int l = 0; l < 20; ++l) {
    const f16* cur = (l % 2 == 0) ? hpA : hpB;
    f16* nxt = (l % 2 == 0) ? hpB : hpA;
    if (pre)
      gemm3<32, true, true><<<256, 512, 0, stream>>>(
          WfH + (size_t)l * 1048576, cur, convs_b + 32 * l, nxt);
    else
      gemm3<32, true, false><<<256, 512, 0, stream>>>(
          convs_w + (size_t)l * 1048576, cur, convs_b + 32 * l, nxt);
  }

  // after l=19 (odd): output in hpA
  out_conv3<<<64, 256, 0, stream>>>(hpA, out_w, out_b, out);
}

// Round 9
// 986.877 us; speedup vs baseline: 1.2314x; 1.2314x over previous
//
#include <hip/hip_runtime.h>

// GoL CNN v10: barrier-free K-loop with PER-WAVE-PRIVATE LDS B-staging.
// Invariant across v4-v9: ~50-60us/layer, all pipes <31%. Remaining walls:
// (a) TA/L1 path: global F-gathers cost 1KB/instr for ~200B distinct (v8/v9);
// (b) cross-wave barrier coupling (v4-v6). v10: each wave stages its OWN 6
// rows/channel (2 masked dwordx4 -> private 2-slot LDS ring), gathers B from
// LDS, A double-buffered in DISJOINT registers (v9 lesson: same-reg refill
// lets the compiler recycle instead of pipeline), pinned by vmcnt fence.
// NO barriers in the K-loop; only the final reduction syncs.

typedef _Float16 f16;
typedef _Float16 f16x8 __attribute__((ext_vector_type(8)));
typedef float f32x4 __attribute__((ext_vector_type(4)));
typedef float f32x16 __attribute__((ext_vector_type(16)));

// iterated wrap-pad index map, j in [0,94): middle j-31; borders alternate.
__device__ __forceinline__ int mwrap(int j) {
  int t = j - 31;
  if ((unsigned)t <= 31u) return t;          // middle
  if (t < 0) return (j & 1) ? 0 : 31;        // left border
  return (j & 1) ? 0 : 31;                   // right border
}

// hpad layout: [16b][32ch][32y][96x] f16 (x' in [0,94) valid)
// Wf frag-major: per layer, chunk=(c*32+ky)*2+kxh, then [lane(64)][8 f16]
//   lane: co=lane&31, s=lane>>5; elements w[co][c][ky][kxh*16+s*8+j]

// 16 MFMAs consuming register-resident fragments (no memory access).
#define MFMAC(AUSE, FD)                                                      \
  {                                                                          \
    _Pragma("unroll")                                                        \
    for (int kyi_ = 0; kyi_ < 4; ++kyi_) {                                   \
      _Pragma("unroll")                                                      \
      for (int kxh_ = 0; kxh_ < 2; ++kxh_) {                                 \
        const f16x8 a_ = AUSE[kyi_ * 2 + kxh_];                              \
        acc0 = __builtin_amdgcn_mfma_f32_32x32x16_f16(a_, FD[kyi_][kxh_],    \
                                                      acc0, 0, 0, 0);        \
        acc1 = __builtin_amdgcn_mfma_f32_32x32x16_f16(a_, FD[kyi_ + 2][kxh_],\
                                                      acc1, 0, 0, 0);        \
      }                                                                      \
    }                                                                        \
  }

// Pin: newest 10 VMEM ops (8 A-loads + 2 stage-loads) may stay in flight;
// everything older (the A-set consumed next) must be complete. "memory"
// clobber forbids sinking the just-issued loads below this point. The
// compiler's waitcnt pass still inserts exact waits for register deps.
#define PIN10()                                          \
  asm volatile("s_waitcnt vmcnt(10)" ::: "memory");      \
  __builtin_amdgcn_sched_barrier(0);

template <int CIN, bool RELU, bool PRE>
__global__ __launch_bounds__(512, 2) void gemm3(
    const void* __restrict__ Wv,       // PRE: f16 frag-major; else fp32 raw
    const f16* __restrict__ hp_in,     // [16][CIN][32][96]
    const float* __restrict__ bias,    // [32]
    f16* __restrict__ hp_out) {        // [16][32][32][96]
  __shared__ float Red[8][2][1024];                 // 64 KB (epilogue only)
  __shared__ __align__(16) f16 Stage[8][2][576];    // per-wave 2-slot ring, 18 KB

  const int tid = threadIdx.x;
  const int lane = tid & 63;
  const int w = tid >> 6;        // wave 0..7: owns ky in {4w..4w+3}
  const int ox = lane & 31;      // B n-index / A m-index (co)
  const int s = lane >> 5;       // k-half within mfma

  const int pair0 = blockIdx.x * 2;
  const int b = pair0 >> 5;
  const int oy0 = pair0 & 31;    // pair0 even -> oy0, oy0+1 same batch

  // ---- per-wave-private staging decode: 6 rows x 96 f16 (=48 dwords/row)
  // unit u = row*12 + seg (72 units of dwordx4); lane covers u=lane, and
  // lanes 0..7 also cover u=64..71.
  const int r0 = lane / 12, g0 = lane - r0 * 12;   // u0 = lane
  const int y0 = mwrap(2 * oy0 + 4 * w + r0);
  const int y5 = mwrap(2 * oy0 + 4 * w + 5);
  const int* hgb = (const int*)hp_in + (size_t)b * CIN * 1536;  // dwords
  const int so0 = y0 * 48 + g0 * 4;                // dword off in channel plane
  const int so1 = y5 * 48 + (4 + lane) * 4;        // lane<8 only
  int* SW = (int*)&Stage[w][0][0];                 // wave's stage base (dwords)
  const int wo0 = r0 * 48 + g0 * 4;                // write dword off (slot-rel)
  const int wo1 = 5 * 48 + (4 + lane) * 4;         // lane<8 only

  // gather: F[j][kxh] = 4 dwords at slot + j*48 + bi (+8 for kxh=1)
  const int bi = ox + 4 * s;

  f32x16 acc0 = {}, acc1 = {};   // per output-row pair
  f16x8 A0[8], A1[8];
  f16x8 F[6][2];
  int4 saA = {}, sbA = {}, saB = {}, sbB = {};

  auto loadA = [&](int c, f16x8* dst) {
#pragma unroll
    for (int kyi = 0; kyi < 4; ++kyi) {
#pragma unroll
      for (int kxh = 0; kxh < 2; ++kxh) {
        const int ky = 4 * w + kyi;
        const int chunk = (c * 32 + ky) * 2 + kxh;
        if constexpr (PRE) {
          const f16* Wl = (const f16*)Wv;
          dst[kyi * 2 + kxh] = *(const f16x8*)(Wl + (size_t)chunk * 512 + lane * 8);
        } else {
          const float* Wl = (const float*)Wv;
          const float* sp = Wl + (((size_t)(ox * CIN + c) * 32 + ky) * 32 + kxh * 16 + s * 8);
          f32x4 u0 = *(const f32x4*)sp;
          f32x4 u1 = *(const f32x4*)(sp + 4);
          f16x8 v;
          v[0] = (f16)u0[0]; v[1] = (f16)u0[1]; v[2] = (f16)u0[2]; v[3] = (f16)u0[3];
          v[4] = (f16)u1[0]; v[5] = (f16)u1[1]; v[6] = (f16)u1[2]; v[7] = (f16)u1[3];
          dst[kyi * 2 + kxh] = v;
        }
      }
    }
  };
  auto loadS = [&](int c, int4& a, int4& bq) {
    const int* p = hgb + c * 1536;
    a = *(const int4*)(p + so0);
    if (lane < 8) bq = *(const int4*)(p + so1);
  };
  auto writeS = [&](int slot, const int4& a, const int4& bq) {
    int* q = SW + slot * 288;
    *(int4*)(q + wo0) = a;
    if (lane < 8) *(int4*)(q + wo1) = bq;
  };
  auto gathF = [&](int slot) {
    const int* q = SW + slot * 288;
#pragma unroll
    for (int j = 0; j < 6; ++j) {
      const int* R = q + j * 48 + bi;
      int4 t0, t1;
      t0.x = R[0]; t0.y = R[1]; t0.z = R[2]; t0.w = R[3];
      t1.x = R[8]; t1.y = R[9]; t1.z = R[10]; t1.w = R[11];
      F[j][0] = __builtin_bit_cast(f16x8, t0);
      F[j][1] = __builtin_bit_cast(f16x8, t1);
    }
  };

  if constexpr (CIN == 1) {
    loadS(0, saA, sbA);
    loadA(0, A0);
    writeS(0, saA, sbA);
    gathF(0);
    MFMAC(A0, F);
  } else {
    static_assert(CIN % 2 == 0, "CIN must be 1 or even");
    loadS(0, saA, sbA);            // S(0)
    loadS(1, saB, sbB);            // S(1) held for slot1 write in sub-0
    loadA(0, A0);
    writeS(0, saA, sbA);
    gathF(0);                      // F = S(0)
#pragma unroll 1
    for (int c = 0; c < CIN; c += 2) {
      // ---- sub c (even; slot0 holds S(c), F = gathered S(c), A0 = A(c))
      loadA(c + 1 < CIN ? c + 1 : CIN - 1, A1);
      loadS(c + 2 < CIN ? c + 2 : CIN - 1, saA, sbA);
      PIN10();
      MFMAC(A0, F);                // channel c
      writeS(1, saB, sbB);         // slot1 <- S(c+1)
      gathF(1);                    // F = S(c+1)
      // ---- sub c+1
      loadA(c + 2 < CIN ? c + 2 : CIN - 1, A0);
      loadS(c + 3 < CIN ? c + 3 : CIN - 1, saB, sbB);
      PIN10();
      MFMAC(A1, F);                // channel c+1
      writeS(0, saA, sbA);         // slot0 <- S(c+2)
      gathF(0);                    // F = S(c+2)
    }
  }

  // one-shot 8-way K reduction: every wave dumps, all 512 threads re-reduce
  __syncthreads();               // first cross-wave sync in the kernel
#pragma unroll
  for (int r = 0; r < 16; ++r) {
    Red[w][0][r * 64 + lane] = acc0[r];
    Red[w][1][r * 64 + lane] = acc1[r];
  }
  __syncthreads();

#pragma unroll
  for (int k4 = 0; k4 < 4; ++k4) {
    const int o = tid + 512 * k4;          // 2048 outputs: [p][co][ox]
    const int p = o >> 10, co = (o >> 5) & 31, oxx = o & 31;
    const int idx = ((co & 3) + 4 * (co >> 3)) * 64 + ((co >> 2) & 1) * 32 + oxx;
    float v = bias[co];
#pragma unroll
    for (int w8 = 0; w8 < 8; ++w8) v += Red[w8][p][idx];
    if (RELU) v = fmaxf(v, 0.f);
    const f16 hv = (f16)v;
    f16* base = hp_out + ((size_t)(b * 32 + co) * 32 + (oy0 + p)) * 96;
    base[oxx + 31] = hv;
    if (oxx == 0) {
#pragma unroll
      for (int j = 1; j <= 29; j += 2) base[j] = hv;
#pragma unroll
      for (int j = 63; j <= 93; j += 2) base[j] = hv;
    }
    if (oxx == 31) {
#pragma unroll
      for (int j = 0; j <= 30; j += 2) base[j] = hv;
#pragma unroll
      for (int j = 64; j <= 92; j += 2) base[j] = hv;
    }
  }
}

// x (fp32 [16][1][32][32]) -> xpad f16 [16][1][32][96]
__global__ void pad_x_kernel(const float* __restrict__ x, f16* __restrict__ xp) {
  const int i = blockIdx.x * 256 + threadIdx.x;  // 16*32*94 = 48128
  if (i >= 48128) return;
  const int bq = i / 3008, r = i - bq * 3008;
  const int y = r / 94, j = r - y * 94;
  xp[bq * 3072 + y * 96 + j] = (f16)x[(bq * 32 + y) * 32 + mwrap(j)];
}

// build frag-major f16 weights: in_w (64 chunks) + 20 hidden layers (2048 each)
__global__ void convert_w3(const float* __restrict__ in_w,
                           const float* __restrict__ convs_w,
                           f16* __restrict__ WfIn, f16* __restrict__ WfH) {
  const int total = 4096 + 20 * 131072;  // units of (chunk,lane)
  for (int g = blockIdx.x * blockDim.x + threadIdx.x; g < total;
       g += gridDim.x * blockDim.x) {
    const float* src;
    f16* dst;
    int chunk, lanE, c, ky, kxh;
    if (g < 4096) {
      chunk = g >> 6; lanE = g & 63;
      kxh = chunk & 1; ky = chunk >> 1; c = 0;
      const int co = lanE & 31, ss = lanE >> 5;
      src = in_w + ((size_t)(co * 1 + 0) * 32 + ky) * 32 + kxh * 16 + ss * 8;
      dst = WfIn + (size_t)chunk * 512 + lanE * 8;
    } else {
      const int h = g - 4096;
      const int layer = h >> 17, r = h & 131071;
      chunk = r >> 6; lanE = r & 63;
      kxh = chunk & 1;
      const int t = chunk >> 1;
      ky = t & 31; c = t >> 5;
      const int co = lanE & 31, ss = lanE >> 5;
      src = convs_w + (size_t)layer * 1048576 +
            ((size_t)(co * 32 + c) * 32 + ky) * 32 + kxh * 16 + ss * 8;
      dst = WfH + (size_t)layer * 1048576 + (size_t)chunk * 512 + lanE * 8;
    }
    f32x4 u0 = *(const f32x4*)src;
    f32x4 u1 = *(const f32x4*)(src + 4);
    f16x8 v;
    v[0] = (f16)u0[0]; v[1] = (f16)u0[1]; v[2] = (f16)u0[2]; v[3] = (f16)u0[3];
    v[4] = (f16)u1[0]; v[5] = (f16)u1[1]; v[6] = (f16)u1[2]; v[7] = (f16)u1[3];
    *(f16x8*)dst = v;
  }
}

// 1x1 out conv from hpad final: out[b][0][oy][ox] fp32
__global__ void out_conv3(const f16* __restrict__ hp,
                          const float* __restrict__ ow,
                          const float* __restrict__ ob,
                          float* __restrict__ out) {
  const int o = blockIdx.x * 256 + threadIdx.x;  // 16384
  const int b = o >> 10, oy = (o >> 5) & 31, oxx = o & 31;
  float s = ob[0];
#pragma unroll
  for (int c = 0; c < 32; ++c)
    s += ow[c] * (float)hp[((size_t)(b * 32 + c) * 32 + oy) * 96 + oxx + 31];
  out[o] = s;
}

extern "C" void kernel_launch(void* const* d_in, const int* in_sizes, int n_in,
                              void* d_out, int out_size, void* d_ws,
                              size_t ws_size, hipStream_t stream) {
  const float* x = (const float*)d_in[0];
  const float* in_w = (const float*)d_in[1];
  const float* in_b = (const float*)d_in[2];
  const float* convs_w = (const float*)d_in[3];
  const float* convs_b = (const float*)d_in[4];
  const float* out_w = (const float*)d_in[5];
  const float* out_b = (const float*)d_in[6];
  float* out = (float*)d_out;

  char* ws = (char*)d_ws;
  f16* xpad = (f16*)ws;                               //    98,304 B
  f16* hpA = (f16*)(ws + 98304);                      // 3,145,728 B
  f16* hpB = (f16*)(ws + 98304 + 3145728);            // 3,145,728 B
  f16* WfIn = (f16*)(ws + 6389760);                   //    65,536 B
  f16* WfH = (f16*)(ws + 6455296);                    // 41,943,040 B
  const bool pre = (ws_size >= 48398336ull);

  pad_x_kernel<<<188, 256, 0, stream>>>(x, xpad);
  if (pre) convert_w3<<<2048, 256, 0, stream>>>(in_w, convs_w, WfIn, WfH);

  if (pre)
    gemm3<1, false, true><<<256, 512, 0, stream>>>(WfIn, xpad, in_b, hpA);
  else
    gemm3<1, false, false><<<256, 512, 0, stream>>>(in_w, xpad, in_b, hpA);

  for (int l = 0; l < 20; ++l) {
    const f16* cur = (l % 2 == 0) ? hpA : hpB;
    f16* nxt = (l % 2 == 0) ? hpB : hpA;
    if (pre)
      gemm3<32, true, true><<<256, 512, 0, stream>>>(
          WfH + (size_t)l * 1048576, cur, convs_b + 32 * l, nxt);
    else
      gemm3<32, true, false><<<256, 512, 0, stream>>>(
          convs_w + (size_t)l * 1048576, cur, convs_b + 32 * l, nxt);
  }

  // after l=19 (odd): output in hpA
  out_conv3<<<64, 256, 0, stream>>>(hpA, out_w, out_b, out);
}

// Round 11
// 864.862 us; speedup vs baseline: 1.4051x; 1.1411x over previous
//
#include <hip/hip_runtime.h>

// GoL CNN v11b: v11 with the staging-row bug fixed.
// v11's asm loadSasm hardcoded the row-5 tail at byte 1024 (assumed y5==5);
// correct is the WRAPPED row y5 = mwrap(2*oy0+4w+5) -> y5*192 + 64 base.
// Everything else identical to v11: inline-asm global_load_dwordx4 (opaque
// defs -> forced distinct regs, cannot sink/recycle), hand-counted
// s_waitcnt vmcnt(10) fences (10 VMEM/channel: 8 A + 2 stage), vmcnt(0)
// drain before epilogue, per-wave-private LDS B-staging, barrier-free K-loop.

typedef _Float16 f16;
typedef _Float16 f16x8 __attribute__((ext_vector_type(8)));
typedef float f32x4 __attribute__((ext_vector_type(4)));
typedef float f32x16 __attribute__((ext_vector_type(16)));
typedef int i32x4 __attribute__((ext_vector_type(4)));

// iterated wrap-pad index map, j in [0,94): middle j-31; borders alternate.
__device__ __forceinline__ int mwrap(int j) {
  int t = j - 31;
  if ((unsigned)t <= 31u) return t;          // middle
  if (t < 0) return (j & 1) ? 0 : 31;        // left border
  return (j & 1) ? 0 : 31;                   // right border
}

// hpad layout: [16b][32ch][32y][96x] f16 (x' in [0,94) valid)
// Wf frag-major: per layer, chunk=(c*32+ky)*2+kxh, then [lane(64)][8 f16]
//   wave w's 8 chunks per channel are CONTIGUOUS: byte c*65536 + w*8192,
//   per-lane 16B at chunk*1024 + lane*16.

// Opaque async 16B load: forced distinct dest regs, cannot be sunk/recycled.
#define GLD16(dst, off, base, imm)                                          \
  asm volatile("global_load_dwordx4 %0, %1, %2 offset:%3"                   \
               : "=v"(dst) : "v"(off), "s"(base), "i"(imm) : "memory")

// Counted fence: wait until <= N VMEM outstanding; block reordering.
#define PINN(N)                                                             \
  asm volatile("s_waitcnt vmcnt(" #N ")" ::: "memory");                     \
  __builtin_amdgcn_sched_barrier(0)

// 16 MFMAs consuming register-resident fragments.
#define MFMAC(AUSE, FD)                                                      \
  {                                                                          \
    __builtin_amdgcn_s_setprio(1);                                           \
    _Pragma("unroll")                                                        \
    for (int kyi_ = 0; kyi_ < 4; ++kyi_) {                                   \
      _Pragma("unroll")                                                      \
      for (int kxh_ = 0; kxh_ < 2; ++kxh_) {                                 \
        const f16x8 a_ = __builtin_bit_cast(f16x8, AUSE[kyi_ * 2 + kxh_]);   \
        acc0 = __builtin_amdgcn_mfma_f32_32x32x16_f16(a_, FD[kyi_][kxh_],    \
                                                      acc0, 0, 0, 0);        \
        acc1 = __builtin_amdgcn_mfma_f32_32x32x16_f16(a_, FD[kyi_ + 2][kxh_],\
                                                      acc1, 0, 0, 0);        \
      }                                                                      \
    }                                                                        \
    __builtin_amdgcn_s_setprio(0);                                           \
  }

template <int CIN, bool RELU, bool PRE>
__global__ __launch_bounds__(512, 2) void gemm3(
    const void* __restrict__ Wv,       // PRE: f16 frag-major; else fp32 raw
    const f16* __restrict__ hp_in,     // [16][CIN][32][96]
    const float* __restrict__ bias,    // [32]
    f16* __restrict__ hp_out) {        // [16][32][32][96]
  __shared__ float Red[8][2][1024];                 // 64 KB (epilogue only)
  __shared__ __align__(16) f16 Stage[8][2][576];    // per-wave 2-slot ring, 18 KB

  const int tid = threadIdx.x;
  const int lane = tid & 63;
  const int w = tid >> 6;        // wave 0..7: owns ky in {4w..4w+3}
  const int ox = lane & 31;      // B n-index / A m-index (co)
  const int s = lane >> 5;       // k-half within mfma

  const int pair0 = blockIdx.x * 2;
  const int b = pair0 >> 5;
  const int oy0 = pair0 & 31;    // pair0 even -> oy0, oy0+1 same batch

  // per-wave-private staging decode: 6 rows x 96 f16 (=48 dwords/row),
  // 72 dwordx4 units; lane covers unit=lane, lanes<8 also unit 64+lane.
  const int r0 = lane / 12, g0 = lane - r0 * 12;
  const int y0 = mwrap(2 * oy0 + 4 * w + r0);
  const int y5 = mwrap(2 * oy0 + 4 * w + 5);
  int* SW = (int*)&Stage[w][0][0];                 // wave's stage base (dwords)
  const int wo0 = r0 * 48 + g0 * 4;                // write dword off (slot-rel)
  const int wo1 = 5 * 48 + (4 + lane) * 4;         // lane<8 only
  const int bi = ox + 4 * s;                       // gather dword offset

  f32x16 acc0 = {}, acc1 = {};
  i32x4 A0[8], A1[8];
  f16x8 F[6][2];
  i32x4 saA = {}, sbA = {}, saB = {}, sbB = {};

  const f16* Wl = (const f16*)Wv;
  const f16* hpb = hp_in + (size_t)b * CIN * 3072;
  const uint32_t aBase = (uint32_t)(w * 8192 + lane * 16);
  const uint32_t s0Base = (uint32_t)(y0 * 192 + g0 * 16);
  // FIX (v11 bug): row-5 tail uses WRAPPED row y5, segs 4..11.
  const uint32_t s1Base = (uint32_t)(y5 * 192 + 64 + (lane & 7) * 16);

  // ---- asm load clusters (PRE path) ----
  auto loadAasm = [&](int c, i32x4* dst) {
    const uint32_t o0 = aBase + (uint32_t)c * 65536u;
    const uint32_t o1 = o0 + 4096u;
    GLD16(dst[0], o0, Wl, 0);    GLD16(dst[1], o0, Wl, 1024);
    GLD16(dst[2], o0, Wl, 2048); GLD16(dst[3], o0, Wl, 3072);
    GLD16(dst[4], o1, Wl, 0);    GLD16(dst[5], o1, Wl, 1024);
    GLD16(dst[6], o1, Wl, 2048); GLD16(dst[7], o1, Wl, 3072);
  };
  auto loadSasm = [&](int c, i32x4& a, i32x4& bq) {
    const uint32_t o0 = s0Base + (uint32_t)c * 6144u;
    const uint32_t o1 = s1Base + (uint32_t)c * 6144u;
    GLD16(a, o0, hpb, 0);
    GLD16(bq, o1, hpb, 0);       // all lanes load (dupes coalesce); <8 write
  };

  // ---- C fallbacks (CIN==1 and non-PRE) ----
  auto loadA_c = [&](int c, i32x4* dst) {
#pragma unroll
    for (int kyi = 0; kyi < 4; ++kyi) {
#pragma unroll
      for (int kxh = 0; kxh < 2; ++kxh) {
        const int ky = 4 * w + kyi;
        const int chunk = (c * 32 + ky) * 2 + kxh;
        if constexpr (PRE) {
          dst[kyi * 2 + kxh] = *(const i32x4*)(Wl + (size_t)chunk * 512 + lane * 8);
        } else {
          const float* Wf = (const float*)Wv;
          const float* sp = Wf + (((size_t)(ox * CIN + c) * 32 + ky) * 32 + kxh * 16 + s * 8);
          f32x4 u0 = *(const f32x4*)sp;
          f32x4 u1 = *(const f32x4*)(sp + 4);
          f16x8 v;
          v[0] = (f16)u0[0]; v[1] = (f16)u0[1]; v[2] = (f16)u0[2]; v[3] = (f16)u0[3];
          v[4] = (f16)u1[0]; v[5] = (f16)u1[1]; v[6] = (f16)u1[2]; v[7] = (f16)u1[3];
          dst[kyi * 2 + kxh] = __builtin_bit_cast(i32x4, v);
        }
      }
    }
  };
  auto loadS_c = [&](int c, i32x4& a, i32x4& bq) {
    const int* p = (const int*)hpb + c * 1536;
    a = *(const i32x4*)(p + (y0 * 48 + g0 * 4));
    if (lane < 8) bq = *(const i32x4*)(p + (y5 * 48 + (4 + lane) * 4));
  };
  auto writeS = [&](int slot, const i32x4& a, const i32x4& bq) {
    int* q = SW + slot * 288;
    *(i32x4*)(q + wo0) = a;
    if (lane < 8) *(i32x4*)(q + wo1) = bq;
  };
  auto gathF = [&](int slot) {
    const int* q = SW + slot * 288;
#pragma unroll
    for (int j = 0; j < 6; ++j) {
      const int* R = q + j * 48 + bi;
      i32x4 t0, t1;
      t0.x = R[0]; t0.y = R[1]; t0.z = R[2]; t0.w = R[3];
      t1.x = R[8]; t1.y = R[9]; t1.z = R[10]; t1.w = R[11];
      F[j][0] = __builtin_bit_cast(f16x8, t0);
      F[j][1] = __builtin_bit_cast(f16x8, t1);
    }
  };

  if constexpr (CIN == 1) {
    loadS_c(0, saA, sbA);
    loadA_c(0, A0);
    writeS(0, saA, sbA);
    gathF(0);
    MFMAC(A0, F);
  } else if constexpr (PRE) {
    static_assert(CIN >= 4 && CIN % 2 == 0, "CIN must be 1 or even >= 4");
    // prologue: outstanding -> {S(0) 2, S(1) 2, A(0) 8} = 12
    loadSasm(0, saA, sbA);
    loadSasm(1, saB, sbB);
    loadAasm(0, A0);
    PINN(10);                    // S(0) complete
    writeS(0, saA, sbA);
    gathF(0);                    // F = B(0)
#pragma unroll 1
    for (int c = 0; c < CIN; c += 2) {
      // entry invariant: outstanding = {A(c) 8, S(c+1) 2}; A0=A(c) regs,
      // F=B(c), saB/sbB=S(c+1) regs.
      const int cA = c + 1 < CIN ? c + 1 : CIN - 1;
      const int cS = c + 2 < CIN ? c + 2 : CIN - 1;
      loadAasm(cA, A1);
      loadSasm(cS, saA, sbA);
      PINN(10);                  // A(c), S(c+1) complete
      MFMAC(A0, F);              // channel c
      writeS(1, saB, sbB);       // slot1 <- S(c+1)
      gathF(1);                  // F = B(c+1)
      const int cA2 = c + 2 < CIN ? c + 2 : CIN - 1;
      const int cS2 = c + 3 < CIN ? c + 3 : CIN - 1;
      loadAasm(cA2, A0);
      loadSasm(cS2, saB, sbB);
      PINN(10);                  // A(c+1), S(c+2) complete
      MFMAC(A1, F);              // channel c+1
      writeS(0, saA, sbA);       // slot0 <- S(c+2)
      gathF(0);                  // F = B(c+2)
    }
    PINN(0);  // drain clamped-tail loads before their regs are reallocated
  } else {
    // non-PRE correctness fallback (not used when workspace is large)
    loadS_c(0, saA, sbA);
    loadS_c(1, saB, sbB);
    loadA_c(0, A0);
    writeS(0, saA, sbA);
    gathF(0);
#pragma unroll 1
    for (int c = 0; c < CIN; c += 2) {
      loadA_c(c + 1 < CIN ? c + 1 : CIN - 1, A1);
      loadS_c(c + 2 < CIN ? c + 2 : CIN - 1, saA, sbA);
      MFMAC(A0, F);
      writeS(1, saB, sbB);
      gathF(1);
      loadA_c(c + 2 < CIN ? c + 2 : CIN - 1, A0);
      loadS_c(c + 3 < CIN ? c + 3 : CIN - 1, saB, sbB);
      MFMAC(A1, F);
      writeS(0, saA, sbA);
      gathF(0);
    }
  }

  // one-shot 8-way K reduction: every wave dumps, all 512 threads re-reduce
  __syncthreads();               // first cross-wave sync in the kernel
#pragma unroll
  for (int r = 0; r < 16; ++r) {
    Red[w][0][r * 64 + lane] = acc0[r];
    Red[w][1][r * 64 + lane] = acc1[r];
  }
  __syncthreads();

#pragma unroll
  for (int k4 = 0; k4 < 4; ++k4) {
    const int o = tid + 512 * k4;          // 2048 outputs: [p][co][ox]
    const int p = o >> 10, co = (o >> 5) & 31, oxx = o & 31;
    const int idx = ((co & 3) + 4 * (co >> 3)) * 64 + ((co >> 2) & 1) * 32 + oxx;
    float v = bias[co];
#pragma unroll
    for (int w8 = 0; w8 < 8; ++w8) v += Red[w8][p][idx];
    if (RELU) v = fmaxf(v, 0.f);
    const f16 hv = (f16)v;
    f16* base = hp_out + ((size_t)(b * 32 + co) * 32 + (oy0 + p)) * 96;
    base[oxx + 31] = hv;
    if (oxx == 0) {
#pragma unroll
      for (int j = 1; j <= 29; j += 2) base[j] = hv;
#pragma unroll
      for (int j = 63; j <= 93; j += 2) base[j] = hv;
    }
    if (oxx == 31) {
#pragma unroll
      for (int j = 0; j <= 30; j += 2) base[j] = hv;
#pragma unroll
      for (int j = 64; j <= 92; j += 2) base[j] = hv;
    }
  }
}

// x (fp32 [16][1][32][32]) -> xpad f16 [16][1][32][96]
__global__ void pad_x_kernel(const float* __restrict__ x, f16* __restrict__ xp) {
  const int i = blockIdx.x * 256 + threadIdx.x;  // 16*32*94 = 48128
  if (i >= 48128) return;
  const int bq = i / 3008, r = i - bq * 3008;
  const int y = r / 94, j = r - y * 94;
  xp[bq * 3072 + y * 96 + j] = (f16)x[(bq * 32 + y) * 32 + mwrap(j)];
}

// build frag-major f16 weights: in_w (64 chunks) + 20 hidden layers (2048 each)
__global__ void convert_w3(const float* __restrict__ in_w,
                           const float* __restrict__ convs_w,
                           f16* __restrict__ WfIn, f16* __restrict__ WfH) {
  const int total = 4096 + 20 * 131072;  // units of (chunk,lane)
  for (int g = blockIdx.x * blockDim.x + threadIdx.x; g < total;
       g += gridDim.x * blockDim.x) {
    const float* src;
    f16* dst;
    int chunk, lanE, c, ky, kxh;
    if (g < 4096) {
      chunk = g >> 6; lanE = g & 63;
      kxh = chunk & 1; ky = chunk >> 1; c = 0;
      const int co = lanE & 31, ss = lanE >> 5;
      src = in_w + ((size_t)(co * 1 + 0) * 32 + ky) * 32 + kxh * 16 + ss * 8;
      dst = WfIn + (size_t)chunk * 512 + lanE * 8;
    } else {
      const int h = g - 4096;
      const int layer = h >> 17, r = h & 131071;
      chunk = r >> 6; lanE = r & 63;
      kxh = chunk & 1;
      const int t = chunk >> 1;
      ky = t & 31; c = t >> 5;
      const int co = lanE & 31, ss = lanE >> 5;
      src = convs_w + (size_t)layer * 1048576 +
            ((size_t)(co * 32 + c) * 32 + ky) * 32 + kxh * 16 + ss * 8;
      dst = WfH + (size_t)layer * 1048576 + (size_t)chunk * 512 + lanE * 8;
    }
    f32x4 u0 = *(const f32x4*)src;
    f32x4 u1 = *(const f32x4*)(src + 4);
    f16x8 v;
    v[0] = (f16)u0[0]; v[1] = (f16)u0[1]; v[2] = (f16)u0[2]; v[3] = (f16)u0[3];
    v[4] = (f16)u1[0]; v[5] = (f16)u1[1]; v[6] = (f16)u1[2]; v[7] = (f16)u1[3];
    *(f16x8*)dst = v;
  }
}

// 1x1 out conv from hpad final: out[b][0][oy][ox] fp32
__global__ void out_conv3(const f16* __restrict__ hp,
                          const float* __restrict__ ow,
                          const float* __restrict__ ob,
                          float* __restrict__ out) {
  const int o = blockIdx.x * 256 + threadIdx.x;  // 16384
  const int b = o >> 10, oy = (o >> 5) & 31, oxx = o & 31;
  float s = ob[0];
#pragma unroll
  for (int c = 0; c < 32; ++c)
    s += ow[c] * (float)hp[((size_t)(b * 32 + c) * 32 + oy) * 96 + oxx + 31];
  out[o] = s;
}

extern "C" void kernel_launch(void* const* d_in, const int* in_sizes, int n_in,
                              void* d_out, int out_size, void* d_ws,
                              size_t ws_size, hipStream_t stream) {
  const float* x = (const float*)d_in[0];
  const float* in_w = (const float*)d_in[1];
  const float* in_b = (const float*)d_in[2];
  const float* convs_w = (const float*)d_in[3];
  const float* convs_b = (const float*)d_in[4];
  const float* out_w = (const float*)d_in[5];
  const float* out_b = (const float*)d_in[6];
  float* out = (float*)d_out;

  char* ws = (char*)d_ws;
  f16* xpad = (f16*)ws;                               //    98,304 B
  f16* hpA = (f16*)(ws + 98304);                      // 3,145,728 B
  f16* hpB = (f16*)(ws + 98304 + 3145728);            // 3,145,728 B
  f16* WfIn = (f16*)(ws + 6389760);                   //    65,536 B
  f16* WfH = (f16*)(ws + 6455296);                    // 41,943,040 B
  const bool pre = (ws_size >= 48398336ull);

  pad_x_kernel<<<188, 256, 0, stream>>>(x, xpad);
  if (pre) convert_w3<<<2048, 256, 0, stream>>>(in_w, convs_w, WfIn, WfH);

  if (pre)
    gemm3<1, false, true><<<256, 512, 0, stream>>>(WfIn, xpad, in_b, hpA);
  else
    gemm3<1, false, false><<<256, 512, 0, stream>>>(in_w, xpad, in_b, hpA);

  for (int l = 0; l < 20; ++l) {
    const f16* cur = (l % 2 == 0) ? hpA : hpB;
    f16* nxt = (l % 2 == 0) ? hpB : hpA;
    if (pre)
      gemm3<32, true, true><<<256, 512, 0, stream>>>(
          WfH + (size_t)l * 1048576, cur, convs_b + 32 * l, nxt);
    else
      gemm3<32, true, false><<<256, 512, 0, stream>>>(
          convs_w + (size_t)l * 1048576, cur, convs_b + 32 * l, nxt);
  }

  // after l=19 (odd): output in hpA
  out_conv3<<<64, 256, 0, stream>>>(hpA, out_w, out_b, out);
}

// Round 12
// 853.405 us; speedup vs baseline: 1.4240x; 1.0134x over previous
//
#include <hip/hip_runtime.h>

// GoL CNN v12: v11b + F-REGISTER double-buffer (LDS gather prefetch).
// v11b proved asm-opaque VMEM double-buffering (PASSED, best total). The
// remaining exposed chain is LDS: gathF ran right before its MFMAs. v12
// gathers channel c+1's fragments BEFORE channel c's MFMA cluster (F0/F1
// alternation) so ds_read latency+issue hide under MFMA. 4-slot LDS ring:
// at channel c: write slot(c+2), gather slot(c+1), compute c. Staging
// distance 3, A distance 1, 10 VMEM/half-iter -> PINN(10) completes
// {A(c), S(c+2)} exactly. LDS ops are C-level (compiler counted lgkm
// waits; same-wave write->read in-order validated by v10/v11b), pinned
// between PINN ("memory" clobber) and sched_barrier(0).

typedef _Float16 f16;
typedef _Float16 f16x8 __attribute__((ext_vector_type(8)));
typedef float f32x4 __attribute__((ext_vector_type(4)));
typedef float f32x16 __attribute__((ext_vector_type(16)));
typedef int i32x4 __attribute__((ext_vector_type(4)));

// iterated wrap-pad index map, j in [0,94): middle j-31; borders alternate.
__device__ __forceinline__ int mwrap(int j) {
  int t = j - 31;
  if ((unsigned)t <= 31u) return t;          // middle
  if (t < 0) return (j & 1) ? 0 : 31;        // left border
  return (j & 1) ? 0 : 31;                   // right border
}

// hpad layout: [16b][32ch][32y][96x] f16 (x' in [0,94) valid)
// Wf frag-major: per layer, chunk=(c*32+ky)*2+kxh, then [lane(64)][8 f16]
//   wave w's 8 chunks per channel are CONTIGUOUS: byte c*65536 + w*8192,
//   per-lane 16B at chunk*1024 + lane*16.

// Opaque async 16B load: forced distinct dest regs, cannot be sunk/recycled.
#define GLD16(dst, off, base, imm)                                          \
  asm volatile("global_load_dwordx4 %0, %1, %2 offset:%3"                   \
               : "=v"(dst) : "v"(off), "s"(base), "i"(imm) : "memory")

// Counted fence: wait until <= N VMEM outstanding; block reordering.
#define PINN(N)                                                             \
  asm volatile("s_waitcnt vmcnt(" #N ")" ::: "memory");                     \
  __builtin_amdgcn_sched_barrier(0)

#define SBAR() __builtin_amdgcn_sched_barrier(0)

// 16 MFMAs consuming register-resident fragments.
#define MFMAC(AUSE, FD)                                                      \
  {                                                                          \
    __builtin_amdgcn_s_setprio(1);                                           \
    _Pragma("unroll")                                                        \
    for (int kyi_ = 0; kyi_ < 4; ++kyi_) {                                   \
      _Pragma("unroll")                                                      \
      for (int kxh_ = 0; kxh_ < 2; ++kxh_) {                                 \
        const f16x8 a_ = __builtin_bit_cast(f16x8, AUSE[kyi_ * 2 + kxh_]);   \
        acc0 = __builtin_amdgcn_mfma_f32_32x32x16_f16(a_, FD[kyi_][kxh_],    \
                                                      acc0, 0, 0, 0);        \
        acc1 = __builtin_amdgcn_mfma_f32_32x32x16_f16(a_, FD[kyi_ + 2][kxh_],\
                                                      acc1, 0, 0, 0);        \
      }                                                                      \
    }                                                                        \
    __builtin_amdgcn_s_setprio(0);                                           \
  }

template <int CIN, bool RELU, bool PRE>
__global__ __launch_bounds__(512, 2) void gemm3(
    const void* __restrict__ Wv,       // PRE: f16 frag-major; else fp32 raw
    const f16* __restrict__ hp_in,     // [16][CIN][32][96]
    const float* __restrict__ bias,    // [32]
    f16* __restrict__ hp_out) {        // [16][32][32][96]
  __shared__ float Red[8][2][1024];                 // 64 KB (epilogue only)
  __shared__ __align__(16) f16 Stage[8][4][576];    // per-wave 4-slot ring, 36 KB

  const int tid = threadIdx.x;
  const int lane = tid & 63;
  const int w = tid >> 6;        // wave 0..7: owns ky in {4w..4w+3}
  const int ox = lane & 31;      // B n-index / A m-index (co)
  const int s = lane >> 5;       // k-half within mfma

  const int pair0 = blockIdx.x * 2;
  const int b = pair0 >> 5;
  const int oy0 = pair0 & 31;    // pair0 even -> oy0, oy0+1 same batch

  // per-wave-private staging decode: 6 rows x 96 f16 (=48 dwords/row),
  // 72 dwordx4 units; lane covers unit=lane, lanes<8 also unit 64+lane.
  const int r0 = lane / 12, g0 = lane - r0 * 12;
  const int y0 = mwrap(2 * oy0 + 4 * w + r0);
  const int y5 = mwrap(2 * oy0 + 4 * w + 5);
  int* SW = (int*)&Stage[w][0][0];                 // wave's stage base (dwords)
  const int wo0 = r0 * 48 + g0 * 4;                // write dword off (slot-rel)
  const int wo1 = 5 * 48 + (4 + lane) * 4;         // lane<8 only
  const int bi = ox + 4 * s;                       // gather dword offset

  f32x16 acc0 = {}, acc1 = {};
  i32x4 A0[8], A1[8];
  f16x8 F0[6][2], F1[6][2];
  i32x4 saA = {}, sbA = {}, saB = {}, sbB = {};

  const f16* Wl = (const f16*)Wv;
  const f16* hpb = hp_in + (size_t)b * CIN * 3072;
  const uint32_t aBase = (uint32_t)(w * 8192 + lane * 16);
  const uint32_t s0Base = (uint32_t)(y0 * 192 + g0 * 16);
  const uint32_t s1Base = (uint32_t)(y5 * 192 + 64 + (lane & 7) * 16);

  // ---- asm load clusters (PRE path) ----
  auto loadAasm = [&](int c, i32x4* dst) {
    const uint32_t o0 = aBase + (uint32_t)c * 65536u;
    const uint32_t o1 = o0 + 4096u;
    GLD16(dst[0], o0, Wl, 0);    GLD16(dst[1], o0, Wl, 1024);
    GLD16(dst[2], o0, Wl, 2048); GLD16(dst[3], o0, Wl, 3072);
    GLD16(dst[4], o1, Wl, 0);    GLD16(dst[5], o1, Wl, 1024);
    GLD16(dst[6], o1, Wl, 2048); GLD16(dst[7], o1, Wl, 3072);
  };
  auto loadSasm = [&](int c, i32x4& a, i32x4& bq) {
    const uint32_t o0 = s0Base + (uint32_t)c * 6144u;
    const uint32_t o1 = s1Base + (uint32_t)c * 6144u;
    GLD16(a, o0, hpb, 0);
    GLD16(bq, o1, hpb, 0);       // all lanes load (dupes coalesce); <8 write
  };

  // ---- C fallbacks (CIN==1 and non-PRE) ----
  auto loadA_c = [&](int c, i32x4* dst) {
#pragma unroll
    for (int kyi = 0; kyi < 4; ++kyi) {
#pragma unroll
      for (int kxh = 0; kxh < 2; ++kxh) {
        const int ky = 4 * w + kyi;
        const int chunk = (c * 32 + ky) * 2 + kxh;
        if constexpr (PRE) {
          dst[kyi * 2 + kxh] = *(const i32x4*)(Wl + (size_t)chunk * 512 + lane * 8);
        } else {
          const float* Wf = (const float*)Wv;
          const float* sp = Wf + (((size_t)(ox * CIN + c) * 32 + ky) * 32 + kxh * 16 + s * 8);
          f32x4 u0 = *(const f32x4*)sp;
          f32x4 u1 = *(const f32x4*)(sp + 4);
          f16x8 v;
          v[0] = (f16)u0[0]; v[1] = (f16)u0[1]; v[2] = (f16)u0[2]; v[3] = (f16)u0[3];
          v[4] = (f16)u1[0]; v[5] = (f16)u1[1]; v[6] = (f16)u1[2]; v[7] = (f16)u1[3];
          dst[kyi * 2 + kxh] = __builtin_bit_cast(i32x4, v);
        }
      }
    }
  };
  auto loadS_c = [&](int c, i32x4& a, i32x4& bq) {
    const int* p = (const int*)hpb + c * 1536;
    a = *(const i32x4*)(p + (y0 * 48 + g0 * 4));
    if (lane < 8) bq = *(const i32x4*)(p + (y5 * 48 + (4 + lane) * 4));
  };
  auto writeS = [&](int slot, const i32x4& a, const i32x4& bq) {
    int* q = SW + slot * 288;
    *(i32x4*)(q + wo0) = a;
    if (lane < 8) *(i32x4*)(q + wo1) = bq;
  };
  auto gathF = [&](int slot, f16x8 (*FD)[2]) {
    const int* q = SW + slot * 288;
#pragma unroll
    for (int j = 0; j < 6; ++j) {
      const int* R = q + j * 48 + bi;
      i32x4 t0, t1;
      t0.x = R[0]; t0.y = R[1]; t0.z = R[2]; t0.w = R[3];
      t1.x = R[8]; t1.y = R[9]; t1.z = R[10]; t1.w = R[11];
      FD[j][0] = __builtin_bit_cast(f16x8, t0);
      FD[j][1] = __builtin_bit_cast(f16x8, t1);
    }
  };

  if constexpr (CIN == 1) {
    loadS_c(0, saA, sbA);
    loadA_c(0, A0);
    writeS(0, saA, sbA);
    gathF(0, F0);
    MFMAC(A0, F0);
  } else if constexpr (PRE) {
    static_assert(CIN >= 6 && CIN % 2 == 0, "CIN must be 1 or even >= 6");
    // prologue: establish invariant {A(0) 8, S(2) 2} outstanding,
    // slots 0,1 = B(0),B(1), F0 = frags of B(0), saA regs = S(2) in flight.
    loadSasm(0, saA, sbA);
    loadSasm(1, saB, sbB);
    loadAasm(0, A0);
    PINN(10);                    // S(0) complete
    writeS(0, saA, sbA);
    loadSasm(2, saA, sbA);
    PINN(10);                    // S(1) complete; out = {A(0) 8, S(2) 2}
    writeS(1, saB, sbB);
    gathF(0, F0);                // B(0) fragments
#pragma unroll 1
    for (int c = 0; c < CIN; c += 2) {
      // ---- even half: compute channel c
      loadAasm(c + 1 < CIN ? c + 1 : CIN - 1, A1);
      loadSasm(c + 3 < CIN ? c + 3 : CIN - 1, saB, sbB);
      PINN(10);                       // A(c), S(c+2) complete
      writeS((c + 2) & 3, saA, sbA);  // slot <- B(c+2)
      gathF((c + 1) & 3, F1);         // F1 <- B(c+1) (written prev half-iter)
      SBAR();
      MFMAC(A0, F0);                  // channel c
      // ---- odd half: compute channel c+1
      loadAasm(c + 2 < CIN ? c + 2 : CIN - 1, A0);
      loadSasm(c + 4 < CIN ? c + 4 : CIN - 1, saA, sbA);
      PINN(10);                       // A(c+1), S(c+3) complete
      writeS((c + 3) & 3, saB, sbB);  // slot <- B(c+3)
      gathF((c + 2) & 3, F0);         // F0 <- B(c+2) (written in even half)
      SBAR();
      MFMAC(A1, F1);                  // channel c+1
    }
    PINN(0);  // drain clamped-tail loads before regs are reallocated
  } else {
    // non-PRE correctness fallback (not used when workspace is large)
    loadS_c(0, saA, sbA);
    loadS_c(1, saB, sbB);
    loadA_c(0, A0);
    writeS(0, saA, sbA);
    gathF(0, F0);
#pragma unroll 1
    for (int c = 0; c < CIN; c += 2) {
      loadA_c(c + 1 < CIN ? c + 1 : CIN - 1, A1);
      loadS_c(c + 2 < CIN ? c + 2 : CIN - 1, saA, sbA);
      MFMAC(A0, F0);
      writeS(1, saB, sbB);
      gathF(1, F0);
      loadA_c(c + 2 < CIN ? c + 2 : CIN - 1, A0);
      loadS_c(c + 3 < CIN ? c + 3 : CIN - 1, saB, sbB);
      MFMAC(A1, F0);
      writeS(0, saA, sbA);
      gathF(0, F0);
    }
  }

  // one-shot 8-way K reduction: every wave dumps, all 512 threads re-reduce
  __syncthreads();               // first cross-wave sync in the kernel
#pragma unroll
  for (int r = 0; r < 16; ++r) {
    Red[w][0][r * 64 + lane] = acc0[r];
    Red[w][1][r * 64 + lane] = acc1[r];
  }
  __syncthreads();

#pragma unroll
  for (int k4 = 0; k4 < 4; ++k4) {
    const int o = tid + 512 * k4;          // 2048 outputs: [p][co][ox]
    const int p = o >> 10, co = (o >> 5) & 31, oxx = o & 31;
    const int idx = ((co & 3) + 4 * (co >> 3)) * 64 + ((co >> 2) & 1) * 32 + oxx;
    float v = bias[co];
#pragma unroll
    for (int w8 = 0; w8 < 8; ++w8) v += Red[w8][p][idx];
    if (RELU) v = fmaxf(v, 0.f);
    const f16 hv = (f16)v;
    f16* base = hp_out + ((size_t)(b * 32 + co) * 32 + (oy0 + p)) * 96;
    base[oxx + 31] = hv;
    if (oxx == 0) {
#pragma unroll
      for (int j = 1; j <= 29; j += 2) base[j] = hv;
#pragma unroll
      for (int j = 63; j <= 93; j += 2) base[j] = hv;
    }
    if (oxx == 31) {
#pragma unroll
      for (int j = 0; j <= 30; j += 2) base[j] = hv;
#pragma unroll
      for (int j = 64; j <= 92; j += 2) base[j] = hv;
    }
  }
}

// x (fp32 [16][1][32][32]) -> xpad f16 [16][1][32][96]
__global__ void pad_x_kernel(const float* __restrict__ x, f16* __restrict__ xp) {
  const int i = blockIdx.x * 256 + threadIdx.x;  // 16*32*94 = 48128
  if (i >= 48128) return;
  const int bq = i / 3008, r = i - bq * 3008;
  const int y = r / 94, j = r - y * 94;
  xp[bq * 3072 + y * 96 + j] = (f16)x[(bq * 32 + y) * 32 + mwrap(j)];
}

// build frag-major f16 weights: in_w (64 chunks) + 20 hidden layers (2048 each)
__global__ void convert_w3(const float* __restrict__ in_w,
                           const float* __restrict__ convs_w,
                           f16* __restrict__ WfIn, f16* __restrict__ WfH) {
  const int total = 4096 + 20 * 131072;  // units of (chunk,lane)
  for (int g = blockIdx.x * blockDim.x + threadIdx.x; g < total;
       g += gridDim.x * blockDim.x) {
    const float* src;
    f16* dst;
    int chunk, lanE, c, ky, kxh;
    if (g < 4096) {
      chunk = g >> 6; lanE = g & 63;
      kxh = chunk & 1; ky = chunk >> 1; c = 0;
      const int co = lanE & 31, ss = lanE >> 5;
      src = in_w + ((size_t)(co * 1 + 0) * 32 + ky) * 32 + kxh * 16 + ss * 8;
      dst = WfIn + (size_t)chunk * 512 + lanE * 8;
    } else {
      const int h = g - 4096;
      const int layer = h >> 17, r = h & 131071;
      chunk = r >> 6; lanE = r & 63;
      kxh = chunk & 1;
      const int t = chunk >> 1;
      ky = t & 31; c = t >> 5;
      const int co = lanE & 31, ss = lanE >> 5;
      src = convs_w + (size_t)layer * 1048576 +
            ((size_t)(co * 32 + c) * 32 + ky) * 32 + kxh * 16 + ss * 8;
      dst = WfH + (size_t)layer * 1048576 + (size_t)chunk * 512 + lanE * 8;
    }
    f32x4 u0 = *(const f32x4*)src;
    f32x4 u1 = *(const f32x4*)(src + 4);
    f16x8 v;
    v[0] = (f16)u0[0]; v[1] = (f16)u0[1]; v[2] = (f16)u0[2]; v[3] = (f16)u0[3];
    v[4] = (f16)u1[0]; v[5] = (f16)u1[1]; v[6] = (f16)u1[2]; v[7] = (f16)u1[3];
    *(f16x8*)dst = v;
  }
}

// 1x1 out conv from hpad final: out[b][0][oy][ox] fp32
__global__ void out_conv3(const f16* __restrict__ hp,
                          const float* __restrict__ ow,
                          const float* __restrict__ ob,
                          float* __restrict__ out) {
  const int o = blockIdx.x * 256 + threadIdx.x;  // 16384
  const int b = o >> 10, oy = (o >> 5) & 31, oxx = o & 31;
  float s = ob[0];
#pragma unroll
  for (int c = 0; c < 32; ++c)
    s += ow[c] * (float)hp[((size_t)(b * 32 + c) * 32 + oy) * 96 + oxx + 31];
  out[o] = s;
}

extern "C" void kernel_launch(void* const* d_in, const int* in_sizes, int n_in,
                              void* d_out, int out_size, void* d_ws,
                              size_t ws_size, hipStream_t stream) {
  const float* x = (const float*)d_in[0];
  const float* in_w = (const float*)d_in[1];
  const float* in_b = (const float*)d_in[2];
  const float* convs_w = (const float*)d_in[3];
  const float* convs_b = (const float*)d_in[4];
  const float* out_w = (const float*)d_in[5];
  const float* out_b = (const float*)d_in[6];
  float* out = (float*)d_out;

  char* ws = (char*)d_ws;
  f16* xpad = (f16*)ws;                               //    98,304 B
  f16* hpA = (f16*)(ws + 98304);                      // 3,145,728 B
  f16* hpB = (f16*)(ws + 98304 + 3145728);            // 3,145,728 B
  f16* WfIn = (f16*)(ws + 6389760);                   //    65,536 B
  f16* WfH = (f16*)(ws + 6455296);                    // 41,943,040 B
  const bool pre = (ws_size >= 48398336ull);

  pad_x_kernel<<<188, 256, 0, stream>>>(x, xpad);
  if (pre) convert_w3<<<2048, 256, 0, stream>>>(in_w, convs_w, WfIn, WfH);

  if (pre)
    gemm3<1, false, true><<<256, 512, 0, stream>>>(WfIn, xpad, in_b, hpA);
  else
    gemm3<1, false, false><<<256, 512, 0, stream>>>(in_w, xpad, in_b, hpA);

  for (int l = 0; l < 20; ++l) {
    const f16* cur = (l % 2 == 0) ? hpA : hpB;
    f16* nxt = (l % 2 == 0) ? hpB : hpA;
    if (pre)
      gemm3<32, true, true><<<256, 512, 0, stream>>>(
          WfH + (size_t)l * 1048576, cur, convs_b + 32 * l, nxt);
    else
      gemm3<32, true, false><<<256, 512, 0, stream>>>(
          convs_w + (size_t)l * 1048576, cur, convs_b + 32 * l, nxt);
  }

  // after l=19 (odd): output in hpA
  out_conv3<<<64, 256, 0, stream>>>(hpA, out_w, out_b, out);
}